// Round 10
// baseline (589.740 us; speedup 1.0000x reference)
//
#include <hip/hip_runtime.h>
#include <cstdint>

constexpr int B    = 256;
constexpr int S    = 33;
constexpr int D    = 42;
constexpr int H    = 128;
constexpr int HFF  = 256;
constexpr int T    = 20;
constexpr int NSTEP = S - 1;   // 32
constexpr int DP   = D / 2;    // 21 f16 d-pairs
constexpr int ADW  = 8192;     // dwords per (s,b) A-slice (e5m2, 32 KB)
constexpr int CH   = 16;       // steps per chunk (A chunk = 128 MiB)
constexpr int NCH  = NSTEP / CH;  // 2 chunks
#define BN_SCALE 0.9999950000374997f

typedef _Float16 h2v __attribute__((ext_vector_type(2)));
typedef _Float16 f16x8 __attribute__((ext_vector_type(8)));
typedef float    f32x4 __attribute__((ext_vector_type(4)));
union UH2 { uint32_t u; h2v h; };

__device__ __forceinline__ float fdot2u(uint32_t a, uint32_t b, float c) {
    UH2 x, y; x.u = a; y.u = b;
    return __builtin_amdgcn_fdot2(x.h, y.h, c, false);
}
__device__ __forceinline__ uint32_t packh2(float a, float b) {
    UH2 u; u.h = h2v{(_Float16)a, (_Float16)b}; return u.u;
}
__device__ __forceinline__ float gelu_exact(float x) {
    return 0.5f * x * (1.0f + erff(x * 0.70710678118654752f));
}
// fast gelu for the hot scan (err ~3e-4, far under the 1e-2 threshold)
__device__ __forceinline__ float gelu_fast(float x) {
    float inner = x * (1.0f + 0.044715f * x * x);
    float E = __expf(1.5957691216f * inner);
    return x * E * __frcp_rn(E + 1.0f);
}
// A-staging swizzle (uint4 index): column ^= (row>>4)<<1 so that L3's
// intra-wave (h = t>>2, g = t&3) reads land 2-way max on LDS banks.
__device__ __forceinline__ int aswz(int idx) {
    return (idx & ~31) | ((idx & 31) ^ (((idx >> 9) & 3) << 1));
}

// ---------------------------------------------------------------------------
// Pack (one-time):
//  wcol[r*512 + t]: weight slices for the QUARTER-K scan (round 10).
//    t -> (jp = t>>2 output-pair, q4 = t&3 input-quarter); thread computes
//    outputs {2jp, 2jp+1} over input quarter q4.
//    r<32  (L0): r = os*16+ipq, ip = q4*16+ipq, o = 2jp+os.
//    32..96 (L1): r-32 = os*32+ipq, ip = q4*32+ipq.
//    96..160(L2): r-96 = os*32+ipq, ip = q4*32+ipq.
//    value = pair (w[2ip][o], w[2ip+1][o]).
//  wp[m][64] f16 (32 dwords/row): A-operand for the MFMA aphase (unchanged).
// ---------------------------------------------------------------------------
__global__ void pack_kernel(const float* __restrict__ w0, const float* __restrict__ w1,
                            const float* __restrict__ w2, const float* __restrict__ w3,
                            uint32_t* __restrict__ wcol, uint32_t* __restrict__ wp) {
    int idx = blockIdx.x * 256 + threadIdx.x;
    if (idx < 160 * 512) {
        int r = idx >> 9, t = idx & 511;
        int jp = t >> 2, q4 = t & 3;
        float a, bb;
        if (r < 32) {
            int os = r >> 4, ipq = r & 15;
            int ip = q4 * 16 + ipq, o = 2 * jp + os;
            a = w0[(2*ip)*HFF + o]; bb = w0[(2*ip+1)*HFF + o];
        } else if (r < 96) {
            int rr = r - 32, os = rr >> 5, ipq = rr & 31;
            int ip = q4 * 32 + ipq, o = 2 * jp + os;
            a = w1[(2*ip)*HFF + o]; bb = w1[(2*ip+1)*HFF + o];
        } else {
            int rr = r - 96, os = rr >> 5, ipq = rr & 31;
            int ip = q4 * 32 + ipq, o = 2 * jp + os;
            a = w2[(2*ip)*HFF + o]; bb = w2[(2*ip+1)*HFF + o];
        }
        wcol[idx] = packh2(a, bb);
    }
    if (idx < 32768 * 32) {
        int m = idx >> 5, dd = (idx & 31) * 2;
        int e = 4 * (m >> 9) + (m & 3);
        int h = (m >> 2) & 127;
        const float* row = w3 + (size_t)e * (H * D) + h * D;
        float a = (dd     < D) ? row[dd]     : 0.f;
        float b = (dd + 1 < D) ? row[dd + 1] : 0.f;
        wp[idx] = packh2(a, b);
    }
}

// ---------------------------------------------------------------------------
// Prep: encoder z0, dxdt padded f16 rows (64 wide, zeros d>=42), bd3g, dt.
// ---------------------------------------------------------------------------
__global__ void prep_kernel(const float* __restrict__ path, const float* __restrict__ ts,
                            const float* __restrict__ ew1, const float* __restrict__ eb1,
                            const float* __restrict__ eg1, const float* __restrict__ ebe1,
                            const float* __restrict__ ew2, const float* __restrict__ eb2,
                            const float* __restrict__ eg2, const float* __restrict__ ebe2,
                            const float* __restrict__ b3,
                            float* __restrict__ zbuf, uint32_t* __restrict__ dxp,
                            float* __restrict__ bd3g, float* __restrict__ dtb) {
    __shared__ float x0[D], hb[H], dxs[NSTEP][D];
    int b = blockIdx.x, tid = threadIdx.x;
    if (tid < D) x0[tid] = path[b * S * D + tid];
    __syncthreads();
    {
        float acc = eb1[tid];
        for (int d = 0; d < D; ++d) acc += x0[d] * ew1[d * H + tid];
        hb[tid] = gelu_exact(acc * (eg1[tid] * BN_SCALE) + ebe1[tid]);
    }
    __syncthreads();
    {
        float acc = eb2[tid];
        for (int i = 0; i < H; ++i) acc += hb[i] * ew2[i * H + tid];
        zbuf[b * H + tid] = acc * (eg2[tid] * BN_SCALE) + ebe2[tid];
    }
    for (int idx = tid; idx < NSTEP * 32; idx += 128) {
        int s = idx >> 5, j2 = idx & 31;
        uint32_t val = 0;
        if (j2 < DP) {
            float dtv = ts[s + 1] - ts[s];
            int base = b * S * D + s * D + 2 * j2;
            float v0 = (path[base + D] - path[base]) / dtv;
            float v1 = (path[base + D + 1] - path[base + 1]) / dtv;
            dxs[s][2 * j2] = v0; dxs[s][2 * j2 + 1] = v1;
            val = packh2(v0, v1);
        }
        dxp[((size_t)(s * B + b)) * 32 + j2] = val;
    }
    __syncthreads();
    for (int s = 0; s < NSTEP; ++s) {
        float a = 0.f;
        for (int d = 0; d < D; ++d) a += b3[tid * D + d] * dxs[s][d];
        bd3g[(size_t)(s * B + b) * H + tid] = a;
    }
    if (b == 0 && tid < NSTEP) dtb[tid] = ts[tid + 1] - ts[tid];
}

// ---------------------------------------------------------------------------
// MFMA A-phase (round-9 version, unchanged): LDS-transpose coalesced stores.
// ---------------------------------------------------------------------------
__global__ void __launch_bounds__(256) amm_kernel(
    const uint32_t* __restrict__ wp, const uint32_t* __restrict__ dxp,
    uint32_t* __restrict__ Ach, int s0) {
    __shared__ __align__(16) uint32_t xpose[4][16 * 36];   // 9.2 KB
    int t = threadIdx.x;
    int l = t & 63, wid = t >> 6;
    int mg = (blockIdx.x & 63) * 4 + wid;        // 0..255
    int sg = blockIdx.x >> 6;                    // 0..31
    int lr = l & 15, lk = l >> 4;
    const char* wpB = (const char*)wp;
    const char* dxB = (const char*)dxp + (size_t)s0 * B * 128;
    char* asB = (char*)Ach;
    uint32_t* xp = xpose[wid];
    f16x8 af0[8], af1[8];
#pragma unroll
    for (int mi = 0; mi < 8; ++mi) {
        const f16x8* p = (const f16x8*)(wpB + ((size_t)(mg * 8 + mi) * 16 + lr) * 128 + lk * 16);
        af0[mi] = p[0]; af1[mi] = p[4];          // d 0..31, d 32..63
    }
#pragma unroll
    for (int si = 0; si < 8; ++si) {
        int q = sg * 128 + si * 16 + lr;         // chunk-local slice (this lane's C col)
#pragma unroll
        for (int mi = 0; mi < 8; ++mi) {
            const f16x8* bp = (const f16x8*)(dxB + (size_t)q * 128 + lk * 16);
            f16x8 b0 = bp[0], b1 = bp[4];
            f32x4 acc = {0.f, 0.f, 0.f, 0.f};
            acc = __builtin_amdgcn_mfma_f32_16x16x32_f16(af0[mi], b0, acc, 0, 0, 0);
            acc = __builtin_amdgcn_mfma_f32_16x16x32_f16(af1[mi], b1, acc, 0, 0, 0);
            uint32_t P0 = packh2(acc[0], acc[1]) + 0x00800080u;
            uint32_t P1 = packh2(acc[2], acc[3]) + 0x00800080u;
            uint32_t Q = __builtin_amdgcn_perm(P1, P0, 0x07050301u);
            xp[lr * 36 + lk + 4 * mi] = Q;
        }
        __syncthreads();
        {
            int qr = l >> 2, seg = l & 3;
            const uint4* src = (const uint4*)(xp + qr * 36 + seg * 8);
            uint4 v0 = src[0], v1 = src[1];
            int qout = sg * 128 + si * 16 + qr;
            char* outB = asB + (size_t)qout * 32768 + mg * 128 + seg * 32;
            *(uint4*)outB = v0;
            *(uint4*)(outB + 16) = v1;
        }
        __syncthreads();
    }
}

// ---------------------------------------------------------------------------
// Scan (per 16-step chunk), round 10: QUARTER-K split.  The round-4/7
// structure was LDS-SERVICE-bound: 48 ds_read_b128/wave/stage (~12 cy each,
// shared pipe) ~= the measured 1480 cy/phase.  Here thread = (jp = t>>2
// output-pair, q4 = t&3 quarter): reads K/4 inputs ONCE, amortized over 2
// outputs -> MLP-phase b128 reads halved (L0 4, L1 8, L2 8 per thread),
// same fdot2 count, reduce via shfl_xor(1)+(2); y/zz writes pair-packed to
// b64.  LDS layouts: zzPd[4][20], y[4][36] (quarter bases hit disjoint bank
// groups; 80/144-B rows keep 16-B alignment).  L3 + A path unchanged.
// ---------------------------------------------------------------------------
__global__ void __launch_bounds__(512, 1)
__attribute__((amdgpu_waves_per_eu(2, 8)))
scan_kernel(
    const uint32_t* __restrict__ wcol, const uint32_t* __restrict__ Ach,
    const float* __restrict__ vb0, const float* __restrict__ vg0, const float* __restrict__ vbe0,
    const float* __restrict__ vb1, const float* __restrict__ vg1, const float* __restrict__ vbe1,
    const float* __restrict__ vb2, const float* __restrict__ vg2, const float* __restrict__ vbe2,
    const float* __restrict__ bd3g, const float* __restrict__ dtb,
    float* __restrict__ zbuf, int s0) {
    __shared__ __align__(16) uint32_t ABUF[2][ADW];            // 64 KB
    __shared__ __align__(16) uint32_t zzPd[80];                // [4 quarters][20]
    __shared__ __align__(16) uint32_t yA[144], yB[144], yC[144]; // [4][36]
    int t = threadIdx.x, b = blockIdx.x;
    int jp = t >> 2, q4 = t & 3;                  // MLP role: outputs 2jp,2jp+1
    int h = t >> 2, g = t & 3;                    // L3/state role (same split)
    int hswz = h ^ (g << 3);                      // swizzled A column
    uint32_t w0h[32], w1h[64], w2h[64];
#pragma unroll
    for (int r = 0; r < 32; ++r) w0h[r] = wcol[r * 512 + t];
#pragma unroll
    for (int r = 0; r < 64; ++r) w1h[r] = wcol[(32 + r) * 512 + t];
#pragma unroll
    for (int r = 0; r < 64; ++r) w2h[r] = wcol[(96 + r) * 512 + t];
    // folded BN for BOTH outputs of the pair: out = gelu(p*cs + co)
    int o0 = 2 * jp, o1 = 2 * jp + 1;
    float c0s0 = vg0[o0] * BN_SCALE, c0o0 = vb0[o0] * c0s0 + vbe0[o0];
    float c0s1 = vg0[o1] * BN_SCALE, c0o1 = vb0[o1] * c0s1 + vbe0[o1];
    float c1s0 = vg1[o0] * BN_SCALE, c1o0 = vb1[o0] * c1s0 + vbe1[o0];
    float c1s1 = vg1[o1] * BN_SCALE, c1o1 = vb1[o1] * c1s1 + vbe1[o1];
    float c2s0 = vg2[o0] * BN_SCALE, c2o0 = vb2[o0] * c2s0 + vbe2[o0];
    float c2s1 = vg2[o1] * BN_SCALE, c2o1 = vb2[o1] * c2s1 + vbe2[o1];
    float zf = zbuf[b * H + h];
    // prologue: stage A for local step 0 (swizzled)
    {
        const uint4* Ag = (const uint4*)(Ach + (size_t)b * ADW);
        uint4 a0 = Ag[t], a1 = Ag[512 + t], a2 = Ag[1024 + t], a3 = Ag[1536 + t];
        uint4* Ad = (uint4*)ABUF[0];
        Ad[aswz(t)] = a0; Ad[aswz(512 + t)] = a1;
        Ad[aswz(1024 + t)] = a2; Ad[aswz(1536 + t)] = a3;
    }
    {
        float zhi = __shfl_down(zf, 4, 64);
        uint32_t pk = packh2(zf, zhi);               // z dword d = t>>3
        uint32_t pk2 = (uint32_t)__shfl_down((int)pk, 8, 64);
        if ((t & 15) == 0) {
            int d = t >> 3;
            uint2 u; u.x = pk; u.y = pk2;
            *(uint2*)&zzPd[(d >> 4) * 20 + (d & 15)] = u;
        }
    }
    __syncthreads();

    for (int sl = 0; sl < CH; ++sl) {
        int s = s0 + sl;
        float hstep = dtb[s];
        float bd3 = bd3g[(size_t)(s * B + b) * H + h];
        // prefetch next step's A into registers (in flight across the step)
        uint4 pf0, pf1, pf2, pf3;
        {
            int sn = (sl + 1 < CH) ? sl + 1 : sl;
            const uint4* Ag = (const uint4*)(Ach + (size_t)(sn * B + b) * ADW);
            pf0 = Ag[t]; pf1 = Ag[512 + t]; pf2 = Ag[1024 + t]; pf3 = Ag[1536 + t];
        }
        const uint32_t* AL = ABUF[sl & 1];
        float ksum = 0.f, kcur = 0.f;
        for (int r = 0; r < 4; ++r) {
            // ---- L0: 128 -> 256 (quarter-K, 2 outputs/thread) ----
            {
                float p0a = 0.f, p0b = 0.f, p1a = 0.f, p1b = 0.f;
                const uint4* zq = (const uint4*)(zzPd + q4 * 20);
#pragma unroll
                for (int u4 = 0; u4 < 4; ++u4) {
                    uint4 zv = zq[u4];
                    p0a = fdot2u(w0h[u4*4+0], zv.x, p0a); p0b = fdot2u(w0h[u4*4+1], zv.y, p0b);
                    p0a = fdot2u(w0h[u4*4+2], zv.z, p0a); p0b = fdot2u(w0h[u4*4+3], zv.w, p0b);
                    p1a = fdot2u(w0h[16+u4*4+0], zv.x, p1a); p1b = fdot2u(w0h[16+u4*4+1], zv.y, p1b);
                    p1a = fdot2u(w0h[16+u4*4+2], zv.z, p1a); p1b = fdot2u(w0h[16+u4*4+3], zv.w, p1b);
                }
                float p0 = p0a + p0b, p1 = p1a + p1b;
                p0 += __shfl_xor(p0, 1, 64); p0 += __shfl_xor(p0, 2, 64);
                p1 += __shfl_xor(p1, 1, 64); p1 += __shfl_xor(p1, 2, 64);
                float v0 = gelu_fast(p0 * c0s0 + c0o0);
                float v1 = gelu_fast(p1 * c0s1 + c0o1);
                uint32_t pk = packh2(v0, v1);        // y dword jp
                uint32_t pk2 = (uint32_t)__shfl_down((int)pk, 4, 64);
                if ((t & 7) == 0) {
                    uint2 u; u.x = pk; u.y = pk2;
                    *(uint2*)&yA[(jp >> 5) * 36 + (jp & 31)] = u;
                }
            }
            __syncthreads();
            // ---- L1: 256 -> 256 (quarter-K, 2 outputs/thread) ----
            {
                float p0a = 0.f, p0b = 0.f, p1a = 0.f, p1b = 0.f;
                const uint4* yq = (const uint4*)(yA + q4 * 36);
#pragma unroll
                for (int u4 = 0; u4 < 8; ++u4) {
                    uint4 yv = yq[u4];
                    p0a = fdot2u(w1h[u4*4+0], yv.x, p0a); p0b = fdot2u(w1h[u4*4+1], yv.y, p0b);
                    p0a = fdot2u(w1h[u4*4+2], yv.z, p0a); p0b = fdot2u(w1h[u4*4+3], yv.w, p0b);
                    p1a = fdot2u(w1h[32+u4*4+0], yv.x, p1a); p1b = fdot2u(w1h[32+u4*4+1], yv.y, p1b);
                    p1a = fdot2u(w1h[32+u4*4+2], yv.z, p1a); p1b = fdot2u(w1h[32+u4*4+3], yv.w, p1b);
                }
                float p0 = p0a + p0b, p1 = p1a + p1b;
                p0 += __shfl_xor(p0, 1, 64); p0 += __shfl_xor(p0, 2, 64);
                p1 += __shfl_xor(p1, 1, 64); p1 += __shfl_xor(p1, 2, 64);
                float v0 = gelu_fast(p0 * c1s0 + c1o0);
                float v1 = gelu_fast(p1 * c1s1 + c1o1);
                uint32_t pk = packh2(v0, v1);
                uint32_t pk2 = (uint32_t)__shfl_down((int)pk, 4, 64);
                if ((t & 7) == 0) {
                    uint2 u; u.x = pk; u.y = pk2;
                    *(uint2*)&yB[(jp >> 5) * 36 + (jp & 31)] = u;
                }
            }
            __syncthreads();
            // ---- L2: 256 -> 256 (quarter-K, 2 outputs/thread) ----
            {
                float p0a = 0.f, p0b = 0.f, p1a = 0.f, p1b = 0.f;
                const uint4* yq = (const uint4*)(yB + q4 * 36);
#pragma unroll
                for (int u4 = 0; u4 < 8; ++u4) {
                    uint4 yv = yq[u4];
                    p0a = fdot2u(w2h[u4*4+0], yv.x, p0a); p0b = fdot2u(w2h[u4*4+1], yv.y, p0b);
                    p0a = fdot2u(w2h[u4*4+2], yv.z, p0a); p0b = fdot2u(w2h[u4*4+3], yv.w, p0b);
                    p1a = fdot2u(w2h[32+u4*4+0], yv.x, p1a); p1b = fdot2u(w2h[32+u4*4+1], yv.y, p1b);
                    p1a = fdot2u(w2h[32+u4*4+2], yv.z, p1a); p1b = fdot2u(w2h[32+u4*4+3], yv.w, p1b);
                }
                float p0 = p0a + p0b, p1 = p1a + p1b;
                p0 += __shfl_xor(p0, 1, 64); p0 += __shfl_xor(p0, 2, 64);
                p1 += __shfl_xor(p1, 1, 64); p1 += __shfl_xor(p1, 2, 64);
                float v0 = gelu_fast(p0 * c2s0 + c2o0);
                float v1 = gelu_fast(p1 * c2s1 + c2o1);
                uint32_t pk = packh2(v0, v1);
                uint32_t pk2 = (uint32_t)__shfl_down((int)pk, 4, 64);
                if ((t & 7) == 0) {
                    uint2 u; u.x = pk; u.y = pk2;
                    *(uint2*)&yC[(jp >> 5) * 36 + (jp & 31)] = u;
                }
            }
            __syncthreads();
            // ---- L3 + state (fused): lane (h,g) covers k-quads
            //      g*16..g*16+15; y quarter g = dwords 32g..32g+31. ----
            {
                float pA = 0.f, pB = 0.f, pC = 0.f, pD = 0.f;
                const uint4* yq = (const uint4*)(yC + g * 36);
#pragma unroll
                for (int kk = 0; kk < 8; ++kk) {
                    uint4 yv = yq[kk];
                    int k0 = g * 16 + 2 * kk;
                    uint32_t Qa = AL[k0 * 128 + hswz];
                    uint32_t Qb = AL[(k0 + 1) * 128 + hswz];
                    pA = fdot2u(__builtin_amdgcn_perm(0u, Qa, 0x010C000Cu), yv.x, pA);
                    pB = fdot2u(__builtin_amdgcn_perm(0u, Qa, 0x030C020Cu), yv.y, pB);
                    pC = fdot2u(__builtin_amdgcn_perm(0u, Qb, 0x010C000Cu), yv.z, pC);
                    pD = fdot2u(__builtin_amdgcn_perm(0u, Qb, 0x030C020Cu), yv.w, pD);
                }
                float ptot = (pA + pB) + (pC + pD);
                ptot += __shfl_xor(ptot, 1, 64);
                ptot += __shfl_xor(ptot, 2, 64);
                kcur = bd3 + ptot;                    // redundant across g-lanes
                float wsm = (r == 1 || r == 2) ? 2.f : 1.f;
                ksum += wsm * kcur;
                float zz;
                if (r < 3) {
                    float cin = (r == 2) ? 1.f : 0.5f;
                    zz = zf + cin * hstep * kcur;
                } else {
                    zf += hstep * (1.f / 6.f) * ksum;
                    zz = zf;
                }
                float zhi = __shfl_down(zz, 4, 64);
                uint32_t pk = packh2(zz, zhi);        // z dword d = t>>3
                uint32_t pk2 = (uint32_t)__shfl_down((int)pk, 8, 64);
                if ((t & 15) == 0) {
                    int d = t >> 3;
                    uint2 u; u.x = pk; u.y = pk2;
                    *(uint2*)&zzPd[(d >> 4) * 20 + (d & 15)] = u;
                }
            }
            if (r == 3) {  // stage prefetched A into the other buffer (swizzled)
                uint4* Ad = (uint4*)ABUF[(sl + 1) & 1];
                Ad[aswz(t)] = pf0; Ad[aswz(512 + t)] = pf1;
                Ad[aswz(1024 + t)] = pf2; Ad[aswz(1536 + t)] = pf3;
            }
            __syncthreads();
        }
    }
    if ((t & 3) == 0) zbuf[b * H + h] = zf;
}

// ---------------------------------------------------------------------------
// attended = (zT@wv+bv)@wo+bo.  One block per sample, 128 threads.
// ---------------------------------------------------------------------------
__global__ void att_kernel(const float* __restrict__ zbuf,
                           const float* __restrict__ wv, const float* __restrict__ bv,
                           const float* __restrict__ wo, const float* __restrict__ bo,
                           float* __restrict__ att) {
    __shared__ float zl[H], v[H];
    int b = blockIdx.x, tid = threadIdx.x;
    zl[tid] = zbuf[b * H + tid];
    __syncthreads();
    {
        float acc = bv[tid];
#pragma unroll 8
        for (int i = 0; i < H; ++i) acc += zl[i] * wv[i * H + tid];
        v[tid] = acc;
    }
    __syncthreads();
    {
        float acc = bo[tid];
#pragma unroll 8
        for (int i = 0; i < H; ++i) acc += v[i] * wo[i * H + tid];
        att[b * H + tid] = acc;
    }
}

// ---------------------------------------------------------------------------
// Decoder: one single-wave block per (t, b).  grid = T*B = 5120.
// ---------------------------------------------------------------------------
__global__ void __launch_bounds__(64) dec_kernel(
    const float* __restrict__ att,
    const float* __restrict__ dw1, const float* __restrict__ db1,
    const float* __restrict__ dw2, const float* __restrict__ db2,
    const float* __restrict__ dw3, const float* __restrict__ db3,
    float* __restrict__ out) {
    int bid = blockIdx.x;
    int t = bid >> 8, b = bid & 255;
    int tid = threadIdx.x;
    __shared__ float al[H], h1l[64];
    al[tid] = att[b * H + tid];
    al[tid + 64] = att[b * H + tid + 64];
    __syncthreads();
    {
        float acc = db1[t * 64 + tid];
#pragma unroll 8
        for (int i = 0; i < H; ++i) acc += al[i] * dw1[t * H * 64 + i * 64 + tid];
        h1l[tid] = gelu_exact(acc);
    }
    __syncthreads();
    float v = 0.f;
    if (tid < 32) {
        float acc = db2[t * 32 + tid];
#pragma unroll 8
        for (int i = 0; i < 64; ++i) acc += h1l[i] * dw2[t * 64 * 32 + i * 32 + tid];
        v = gelu_exact(acc) * dw3[t * 32 + tid];
    }
#pragma unroll
    for (int off = 16; off >= 1; off >>= 1) v += __shfl_down(v, off, 64);
    if (tid == 0) out[b * T + t] = 1.f / (1.f + expf(-(v + db3[t])));
}

// ---------------------------------------------------------------------------
extern "C" void kernel_launch(void* const* d_in, const int* in_sizes, int n_in,
                              void* d_out, int out_size, void* d_ws, size_t ws_size,
                              hipStream_t stream) {
    const float* path = (const float*)d_in[0];
    const float* ts   = (const float*)d_in[1];
    const float* ew1  = (const float*)d_in[2];
    const float* eb1  = (const float*)d_in[3];
    const float* eg1  = (const float*)d_in[4];
    const float* ebe1 = (const float*)d_in[5];
    const float* ew2  = (const float*)d_in[6];
    const float* eb2  = (const float*)d_in[7];
    const float* eg2  = (const float*)d_in[8];
    const float* ebe2 = (const float*)d_in[9];
    const float* vw0  = (const float*)d_in[10];
    const float* vb0  = (const float*)d_in[11];
    const float* vg0  = (const float*)d_in[12];
    const float* vbe0 = (const float*)d_in[13];
    const float* vw1  = (const float*)d_in[14];
    const float* vb1  = (const float*)d_in[15];
    const float* vg1  = (const float*)d_in[16];
    const float* vbe1 = (const float*)d_in[17];
    const float* vw2  = (const float*)d_in[18];
    const float* vb2  = (const float*)d_in[19];
    const float* vg2  = (const float*)d_in[20];
    const float* vbe2 = (const float*)d_in[21];
    const float* vw3  = (const float*)d_in[22];
    const float* vb3  = (const float*)d_in[23];
    const float* wv   = (const float*)d_in[24];
    const float* bv   = (const float*)d_in[25];
    const float* wo   = (const float*)d_in[26];
    const float* bo   = (const float*)d_in[27];
    const float* dw1  = (const float*)d_in[28];
    const float* db1  = (const float*)d_in[29];
    const float* dw2  = (const float*)d_in[30];
    const float* db2  = (const float*)d_in[31];
    const float* dw3  = (const float*)d_in[32];
    const float* db3  = (const float*)d_in[33];

    char* ws = (char*)d_ws;
    size_t off = 0;
    auto take = [&](size_t bytes) { char* p = ws + off; off += (bytes + 255) & ~(size_t)255; return p; };
    uint32_t* Ach   = (uint32_t*)take((size_t)CH * B * ADW * 4);    // 128 MiB
    uint32_t* dxp   = (uint32_t*)take((size_t)NSTEP * B * 32 * 4);  // 1 MiB (padded rows)
    float*    bd3g  = (float*)take((size_t)NSTEP * B * H * 4);      // 4 MiB
    float*    dtb   = (float*)take(NSTEP * 4);
    float*    zbuf  = (float*)take((size_t)B * H * 4);
    float*    att   = (float*)take((size_t)B * H * 4);
    uint32_t* wcol  = (uint32_t*)take((size_t)160 * 512 * 4);       // 320 KB
    uint32_t* wp    = (uint32_t*)take((size_t)32768 * 32 * 4);      // 4 MiB

    pack_kernel<<<(32768 * 32 + 255) / 256, 256, 0, stream>>>(vw0, vw1, vw2, vw3, wcol, wp);
    prep_kernel<<<B, 128, 0, stream>>>(path, ts, ew1, eb1, eg1, ebe1,
                                       ew2, eb2, eg2, ebe2, vb3, zbuf, dxp, bd3g, dtb);
    for (int c = 0; c < NCH; ++c) {
        amm_kernel<<<2048, 256, 0, stream>>>(wp, dxp, Ach, c * CH);
        scan_kernel<<<B, 512, 0, stream>>>(wcol, Ach,
                                           vb0, vg0, vbe0, vb1, vg1, vbe1, vb2, vg2, vbe2,
                                           bd3g, dtb, zbuf, c * CH);
    }
    att_kernel<<<B, 128, 0, stream>>>(zbuf, wv, bv, wo, bo, att);
    dec_kernel<<<T * B, 64, 0, stream>>>(att, dw1, db1, dw2, db2, dw3, db3, (float*)d_out);
}

// Round 11
// 530.176 us; speedup vs baseline: 1.1123x; 1.1123x over previous
//
#include <hip/hip_runtime.h>
#include <cstdint>

constexpr int B    = 256;
constexpr int S    = 33;
constexpr int D    = 42;
constexpr int H    = 128;
constexpr int HFF  = 256;
constexpr int T    = 20;
constexpr int NSTEP = S - 1;   // 32
constexpr int DP   = D / 2;    // 21 f16 d-pairs
constexpr int ADW  = 8192;     // dwords per (s,b) A-slice (e5m2, 32 KB)
constexpr int CH   = 16;       // steps per chunk (A chunk = 128 MiB)
constexpr int NCH  = NSTEP / CH;  // 2 chunks
#define BN_SCALE 0.9999950000374997f

typedef _Float16 h2v __attribute__((ext_vector_type(2)));
typedef _Float16 f16x8 __attribute__((ext_vector_type(8)));
typedef float    f32x4 __attribute__((ext_vector_type(4)));
union UH2 { uint32_t u; h2v h; };

__device__ __forceinline__ float fdot2u(uint32_t a, uint32_t b, float c) {
    UH2 x, y; x.u = a; y.u = b;
    return __builtin_amdgcn_fdot2(x.h, y.h, c, false);
}
__device__ __forceinline__ uint32_t packh2(float a, float b) {
    UH2 u; u.h = h2v{(_Float16)a, (_Float16)b}; return u.u;
}
__device__ __forceinline__ float gelu_exact(float x) {
    return 0.5f * x * (1.0f + erff(x * 0.70710678118654752f));
}
// fast gelu for the hot scan (err ~3e-4, far under the 1e-2 threshold)
__device__ __forceinline__ float gelu_fast(float x) {
    float inner = x * (1.0f + 0.044715f * x * x);
    float E = __expf(1.5957691216f * inner);
    return x * E * __frcp_rn(E + 1.0f);
}
// A-staging swizzle (uint4 index): column ^= (row>>4)<<1 so that L3's
// intra-wave (h = t>>2, g = t&3) reads land 2-way max on LDS banks.
__device__ __forceinline__ int aswz(int idx) {
    return (idx & ~31) | ((idx & 31) ^ (((idx >> 9) & 3) << 1));
}

// ---------------------------------------------------------------------------
// Merged one-time pack + prep (saves one dispatch + launch gap).
// Blocks [0, 4096): pack role —
//   wcol[r*512 + t]: f16-pair weight-column slices for the 512-thread scan
//     (r7/r9 HALF-K layout).  t -> (j = t>>1, half = t&1).  r<32: w0
//     ip=half*32+r; r in [32,96): w1 ip=half*64+(r-32); r in [96,160): w2
//     ip=half*64+(r-96).  pair = (w[2ip][j], w[2ip+1][j]).
//   wp[m][64] f16 (32 dwords/row): A-operand for the MFMA aphase.
//     m: e = 4*(m>>9)+(m&3); h = (m>>2)&127; wp[m][d] = w3[e][h*D+d] (0-pad).
// Blocks [4096, 4096+B): prep role (b = blockIdx-4096, 256 threads) —
//   encoder z0, dxdt padded f16 rows (64 wide, zeros d>=42), bd3g, dt.
// ---------------------------------------------------------------------------
__global__ void __launch_bounds__(256) packprep_kernel(
    const float* __restrict__ w0, const float* __restrict__ w1,
    const float* __restrict__ w2, const float* __restrict__ w3,
    uint32_t* __restrict__ wcol, uint32_t* __restrict__ wp,
    const float* __restrict__ path, const float* __restrict__ ts,
    const float* __restrict__ ew1, const float* __restrict__ eb1,
    const float* __restrict__ eg1, const float* __restrict__ ebe1,
    const float* __restrict__ ew2, const float* __restrict__ eb2,
    const float* __restrict__ eg2, const float* __restrict__ ebe2,
    const float* __restrict__ b3,
    float* __restrict__ zbuf, uint32_t* __restrict__ dxp,
    float* __restrict__ bd3g, float* __restrict__ dtb) {
    int tid = threadIdx.x;
    if (blockIdx.x < 4096) {
        // ---------------- pack role ----------------
        int idx = blockIdx.x * 256 + tid;
        if (idx < 160 * 512) {
            int r = idx >> 9, t = idx & 511;
            int j = t >> 1, half = t & 1;
            float a, bb;
            if (r < 32)      { int ip = half * 32 + r;      a = w0[(2*ip)*HFF + j]; bb = w0[(2*ip+1)*HFF + j]; }
            else if (r < 96) { int ip = half * 64 + (r-32); a = w1[(2*ip)*HFF + j]; bb = w1[(2*ip+1)*HFF + j]; }
            else             { int ip = half * 64 + (r-96); a = w2[(2*ip)*HFF + j]; bb = w2[(2*ip+1)*HFF + j]; }
            wcol[idx] = packh2(a, bb);
        }
        if (idx < 32768 * 32) {
            int m = idx >> 5, dd = (idx & 31) * 2;
            int e = 4 * (m >> 9) + (m & 3);
            int h = (m >> 2) & 127;
            const float* row = w3 + (size_t)e * (H * D) + h * D;
            float a = (dd     < D) ? row[dd]     : 0.f;
            float b = (dd + 1 < D) ? row[dd + 1] : 0.f;
            wp[idx] = packh2(a, b);
        }
        return;
    }
    // ---------------- prep role (256 threads) ----------------
    __shared__ float x0[D], hb[H], dxs[NSTEP][D];
    int b = blockIdx.x - 4096;
    if (tid < D) x0[tid] = path[b * S * D + tid];
    __syncthreads();
    if (tid < H) {
        float acc = eb1[tid];
        for (int d = 0; d < D; ++d) acc += x0[d] * ew1[d * H + tid];
        hb[tid] = gelu_exact(acc * (eg1[tid] * BN_SCALE) + ebe1[tid]);
    }
    __syncthreads();
    if (tid < H) {
        float acc = eb2[tid];
        for (int i = 0; i < H; ++i) acc += hb[i] * ew2[i * H + tid];
        zbuf[b * H + tid] = acc * (eg2[tid] * BN_SCALE) + ebe2[tid];
    }
    for (int idx = tid; idx < NSTEP * 32; idx += 256) {
        int s = idx >> 5, j2 = idx & 31;
        uint32_t val = 0;
        if (j2 < DP) {
            float dtv = ts[s + 1] - ts[s];
            int base = b * S * D + s * D + 2 * j2;
            float v0 = (path[base + D] - path[base]) / dtv;
            float v1 = (path[base + D + 1] - path[base + 1]) / dtv;
            dxs[s][2 * j2] = v0; dxs[s][2 * j2 + 1] = v1;
            val = packh2(v0, v1);
        }
        dxp[((size_t)(s * B + b)) * 32 + j2] = val;
    }
    __syncthreads();
    if (tid < H) {
        for (int s = 0; s < NSTEP; ++s) {
            float a = 0.f;
            for (int d = 0; d < D; ++d) a += b3[tid * D + d] * dxs[s][d];
            bd3g[(size_t)(s * B + b) * H + tid] = a;
        }
    }
    if (b == 0 && tid < NSTEP) dtb[tid] = ts[tid + 1] - ts[tid];
}

// ---------------------------------------------------------------------------
// MFMA A-phase (round-9 version, unchanged): LDS-transpose coalesced stores.
// ---------------------------------------------------------------------------
__global__ void __launch_bounds__(256) amm_kernel(
    const uint32_t* __restrict__ wp, const uint32_t* __restrict__ dxp,
    uint32_t* __restrict__ Ach, int s0) {
    __shared__ __align__(16) uint32_t xpose[4][16 * 36];   // 9.2 KB
    int t = threadIdx.x;
    int l = t & 63, wid = t >> 6;
    int mg = (blockIdx.x & 63) * 4 + wid;        // 0..255
    int sg = blockIdx.x >> 6;                    // 0..31
    int lr = l & 15, lk = l >> 4;
    const char* wpB = (const char*)wp;
    const char* dxB = (const char*)dxp + (size_t)s0 * B * 128;
    char* asB = (char*)Ach;
    uint32_t* xp = xpose[wid];
    f16x8 af0[8], af1[8];
#pragma unroll
    for (int mi = 0; mi < 8; ++mi) {
        const f16x8* p = (const f16x8*)(wpB + ((size_t)(mg * 8 + mi) * 16 + lr) * 128 + lk * 16);
        af0[mi] = p[0]; af1[mi] = p[4];          // d 0..31, d 32..63
    }
#pragma unroll
    for (int si = 0; si < 8; ++si) {
        int q = sg * 128 + si * 16 + lr;         // chunk-local slice (this lane's C col)
#pragma unroll
        for (int mi = 0; mi < 8; ++mi) {
            const f16x8* bp = (const f16x8*)(dxB + (size_t)q * 128 + lk * 16);
            f16x8 b0 = bp[0], b1 = bp[4];
            f32x4 acc = {0.f, 0.f, 0.f, 0.f};
            acc = __builtin_amdgcn_mfma_f32_16x16x32_f16(af0[mi], b0, acc, 0, 0, 0);
            acc = __builtin_amdgcn_mfma_f32_16x16x32_f16(af1[mi], b1, acc, 0, 0, 0);
            uint32_t P0 = packh2(acc[0], acc[1]) + 0x00800080u;
            uint32_t P1 = packh2(acc[2], acc[3]) + 0x00800080u;
            uint32_t Q = __builtin_amdgcn_perm(P1, P0, 0x07050301u);
            xp[lr * 36 + lk + 4 * mi] = Q;
        }
        __syncthreads();
        {
            int qr = l >> 2, seg = l & 3;
            const uint4* src = (const uint4*)(xp + qr * 36 + seg * 8);
            uint4 v0 = src[0], v1 = src[1];
            int qout = sg * 128 + si * 16 + qr;
            char* outB = asB + (size_t)qout * 32768 + mg * 128 + seg * 32;
            *(uint4*)outB = v0;
            *(uint4*)(outB + 16) = v1;
        }
        __syncthreads();
    }
}

// ---------------------------------------------------------------------------
// Scan (per 16-step chunk): round-7/9 structure VERBATIM (proven 158.6 us,
// VGPR 120, no spill; 6 alternative scan structures all regressed or were
// neutral — r1-r4, r6, r8, r10).  512 thr, 4 fused phases/stage, 4-acc ILP,
// fused L3+state via (h = t>>2, g = t&3) lane map, aswz A-swizzle.
// NEW: when do_att != 0 (last chunk), computes attended = (zT@wv+bv)@wo+bo
// in an epilogue (zT already in-register; saves the att dispatch + gap).
// ---------------------------------------------------------------------------
__global__ void __launch_bounds__(512, 1)
__attribute__((amdgpu_waves_per_eu(2, 8)))
scan_kernel(
    const uint32_t* __restrict__ wcol, const uint32_t* __restrict__ Ach,
    const float* __restrict__ vb0, const float* __restrict__ vg0, const float* __restrict__ vbe0,
    const float* __restrict__ vb1, const float* __restrict__ vg1, const float* __restrict__ vbe1,
    const float* __restrict__ vb2, const float* __restrict__ vg2, const float* __restrict__ vbe2,
    const float* __restrict__ bd3g, const float* __restrict__ dtb,
    float* __restrict__ zbuf, int s0, int do_att,
    const float* __restrict__ wv, const float* __restrict__ bv,
    const float* __restrict__ wo, const float* __restrict__ bo,
    float* __restrict__ att) {
    __shared__ __align__(16) uint32_t ABUF[2][ADW];            // 64 KB
    __shared__ __align__(16) uint32_t zzPd[72];                // half*36 + r
    __shared__ __align__(16) uint32_t yA[136], yB[136], yC[136]; // half*68 + r
    __shared__ float zfl[H], vv[H];                            // att epilogue
    int t = threadIdx.x, b = blockIdx.x;
    int j = t >> 1, half = t & 1;                     // MLP role
    int h = t >> 2, g = t & 3;                        // L3/state role
    int hswz = h ^ (g << 3);                          // swizzled A column
    uint32_t w0h[32], w1h[64], w2h[64];
#pragma unroll
    for (int r = 0; r < 32; ++r) w0h[r] = wcol[r * 512 + t];
#pragma unroll
    for (int r = 0; r < 64; ++r) w1h[r] = wcol[(32 + r) * 512 + t];
#pragma unroll
    for (int r = 0; r < 64; ++r) w2h[r] = wcol[(96 + r) * 512 + t];
    // folded BN: out = gelu(p*cs + co)
    float c0s = vg0[j] * BN_SCALE, c0o = vb0[j] * c0s + vbe0[j];
    float c1s = vg1[j] * BN_SCALE, c1o = vb1[j] * c1s + vbe1[j];
    float c2s = vg2[j] * BN_SCALE, c2o = vb2[j] * c2s + vbe2[j];
    float zf = zbuf[b * H + h];
    // prologue: stage A for local step 0 (swizzled)
    {
        const uint4* Ag = (const uint4*)(Ach + (size_t)b * ADW);
        uint4 a0 = Ag[t], a1 = Ag[512 + t], a2 = Ag[1024 + t], a3 = Ag[1536 + t];
        uint4* Ad = (uint4*)ABUF[0];
        Ad[aswz(t)] = a0; Ad[aswz(512 + t)] = a1;
        Ad[aswz(1024 + t)] = a2; Ad[aswz(1536 + t)] = a3;
    }
    {
        float zhi = __shfl_down(zf, 4, 64);
        if ((t & 7) == 0) {
            int ip = t >> 3;
            zzPd[(ip >> 5) * 36 + (ip & 31)] = packh2(zf, zhi);
        }
    }
    __syncthreads();

    for (int sl = 0; sl < CH; ++sl) {
        int s = s0 + sl;
        float hstep = dtb[s];
        float bd3 = bd3g[(size_t)(s * B + b) * H + h];
        // prefetch next step's A into registers (in flight across the step)
        uint4 pf0, pf1, pf2, pf3;
        {
            int sn = (sl + 1 < CH) ? sl + 1 : sl;
            const uint4* Ag = (const uint4*)(Ach + (size_t)(sn * B + b) * ADW);
            pf0 = Ag[t]; pf1 = Ag[512 + t]; pf2 = Ag[1024 + t]; pf3 = Ag[1536 + t];
        }
        const uint32_t* AL = ABUF[sl & 1];
        float ksum = 0.f, kcur = 0.f;
        for (int r = 0; r < 4; ++r) {
            // ---- L0: 128 -> 256 (half-K per lane, 4 accumulators) ----
            {
                float pa = 0.f, pb = 0.f, pc = 0.f, pd = 0.f;
                const uint4* zq = (const uint4*)(zzPd + half * 36);
#pragma unroll
                for (int u4 = 0; u4 < 8; ++u4) {
                    uint4 zv = zq[u4];
                    pa = fdot2u(w0h[4*u4+0], zv.x, pa); pb = fdot2u(w0h[4*u4+1], zv.y, pb);
                    pc = fdot2u(w0h[4*u4+2], zv.z, pc); pd = fdot2u(w0h[4*u4+3], zv.w, pd);
                }
                float p = (pa + pb) + (pc + pd);
                p += __shfl_xor(p, 1, 64);
                float v = gelu_fast(p * c0s + c0o);
                float vhi = __shfl_down(v, 2, 64);
                if ((t & 3) == 0) {
                    int ip = t >> 2;
                    yA[(ip >> 6) * 68 + (ip & 63)] = packh2(v, vhi);
                }
            }
            __syncthreads();
            // ---- L1: 256 -> 256 (4 accumulators) ----
            {
                float pa = 0.f, pb = 0.f, pc = 0.f, pd = 0.f;
                const uint4* yq = (const uint4*)(yA + half * 68);
#pragma unroll
                for (int u4 = 0; u4 < 16; ++u4) {
                    uint4 yv = yq[u4];
                    pa = fdot2u(w1h[4*u4+0], yv.x, pa); pb = fdot2u(w1h[4*u4+1], yv.y, pb);
                    pc = fdot2u(w1h[4*u4+2], yv.z, pc); pd = fdot2u(w1h[4*u4+3], yv.w, pd);
                }
                float p = (pa + pb) + (pc + pd);
                p += __shfl_xor(p, 1, 64);
                float v = gelu_fast(p * c1s + c1o);
                float vhi = __shfl_down(v, 2, 64);
                if ((t & 3) == 0) {
                    int ip = t >> 2;
                    yB[(ip >> 6) * 68 + (ip & 63)] = packh2(v, vhi);
                }
            }
            __syncthreads();
            // ---- L2: 256 -> 256 (4 accumulators) ----
            {
                float pa = 0.f, pb = 0.f, pc = 0.f, pd = 0.f;
                const uint4* yq = (const uint4*)(yB + half * 68);
#pragma unroll
                for (int u4 = 0; u4 < 16; ++u4) {
                    uint4 yv = yq[u4];
                    pa = fdot2u(w2h[4*u4+0], yv.x, pa); pb = fdot2u(w2h[4*u4+1], yv.y, pb);
                    pc = fdot2u(w2h[4*u4+2], yv.z, pc); pd = fdot2u(w2h[4*u4+3], yv.w, pd);
                }
                float p = (pa + pb) + (pc + pd);
                p += __shfl_xor(p, 1, 64);
                float v = gelu_fast(p * c2s + c2o);
                float vhi = __shfl_down(v, 2, 64);
                if ((t & 3) == 0) {
                    int ip = t >> 2;
                    yC[(ip >> 6) * 68 + (ip & 63)] = packh2(v, vhi);
                }
            }
            __syncthreads();
            // ---- L3 + state (fused): lane (h = t>>2, g = t&3) covers
            //      k-quads g*16..g*16+15; intra-wave reduce over g. ----
            {
                float pA = 0.f, pB = 0.f, pC = 0.f, pD = 0.f;
                int ybase = (g >> 1) * 68 + (g & 1) * 32;
                const uint4* yq = (const uint4*)(yC + ybase);
#pragma unroll
                for (int kk = 0; kk < 8; ++kk) {
                    uint4 yv = yq[kk];
                    int k0 = g * 16 + 2 * kk;
                    uint32_t Qa = AL[k0 * 128 + hswz];
                    uint32_t Qb = AL[(k0 + 1) * 128 + hswz];
                    pA = fdot2u(__builtin_amdgcn_perm(0u, Qa, 0x010C000Cu), yv.x, pA);
                    pB = fdot2u(__builtin_amdgcn_perm(0u, Qa, 0x030C020Cu), yv.y, pB);
                    pC = fdot2u(__builtin_amdgcn_perm(0u, Qb, 0x010C000Cu), yv.z, pC);
                    pD = fdot2u(__builtin_amdgcn_perm(0u, Qb, 0x030C020Cu), yv.w, pD);
                }
                float ptot = (pA + pB) + (pC + pD);
                ptot += __shfl_xor(ptot, 1, 64);
                ptot += __shfl_xor(ptot, 2, 64);
                kcur = bd3 + ptot;                    // redundant across g-lanes
                float wsm = (r == 1 || r == 2) ? 2.f : 1.f;
                ksum += wsm * kcur;
                float zz;
                if (r < 3) {
                    float cin = (r == 2) ? 1.f : 0.5f;
                    zz = zf + cin * hstep * kcur;
                } else {
                    zf += hstep * (1.f / 6.f) * ksum;
                    zz = zf;
                }
                float zhi = __shfl_down(zz, 4, 64);
                if ((t & 7) == 0) {
                    int ip = t >> 3;
                    zzPd[(ip >> 5) * 36 + (ip & 31)] = packh2(zz, zhi);
                }
            }
            if (r == 3) {  // stage prefetched A into the other buffer (swizzled)
                uint4* Ad = (uint4*)ABUF[(sl + 1) & 1];
                Ad[aswz(t)] = pf0; Ad[aswz(512 + t)] = pf1;
                Ad[aswz(1024 + t)] = pf2; Ad[aswz(1536 + t)] = pf3;
            }
            __syncthreads();
        }
    }
    if ((t & 3) == 0) zbuf[b * H + h] = zf;
    if (do_att) {
        // attended = (zT@wv + bv)@wo + bo.  thread (h = t>>2, g = t&3):
        // quarter-dot over i in [32g, 32g+32), reduce via shfl_xor(1,2).
        if ((t & 3) == 0) zfl[h] = zf;
        __syncthreads();
        {
            float acc = 0.f;
            int i0 = 32 * g;
#pragma unroll 8
            for (int i = 0; i < 32; ++i) acc += zfl[i0 + i] * wv[(i0 + i) * H + h];
            acc += __shfl_xor(acc, 1, 64);
            acc += __shfl_xor(acc, 2, 64);
            if (g == 0) vv[h] = acc + bv[h];
        }
        __syncthreads();
        {
            float acc = 0.f;
            int i0 = 32 * g;
#pragma unroll 8
            for (int i = 0; i < 32; ++i) acc += vv[i0 + i] * wo[(i0 + i) * H + h];
            acc += __shfl_xor(acc, 1, 64);
            acc += __shfl_xor(acc, 2, 64);
            if (g == 0) att[b * H + h] = acc + bo[h];
        }
    }
}

// ---------------------------------------------------------------------------
// Decoder: one single-wave block per (t, b).  grid = T*B = 5120.
// ---------------------------------------------------------------------------
__global__ void __launch_bounds__(64) dec_kernel(
    const float* __restrict__ att,
    const float* __restrict__ dw1, const float* __restrict__ db1,
    const float* __restrict__ dw2, const float* __restrict__ db2,
    const float* __restrict__ dw3, const float* __restrict__ db3,
    float* __restrict__ out) {
    int bid = blockIdx.x;
    int t = bid >> 8, b = bid & 255;
    int tid = threadIdx.x;
    __shared__ float al[H], h1l[64];
    al[tid] = att[b * H + tid];
    al[tid + 64] = att[b * H + tid + 64];
    __syncthreads();
    {
        float acc = db1[t * 64 + tid];
#pragma unroll 8
        for (int i = 0; i < H; ++i) acc += al[i] * dw1[t * H * 64 + i * 64 + tid];
        h1l[tid] = gelu_exact(acc);
    }
    __syncthreads();
    float v = 0.f;
    if (tid < 32) {
        float acc = db2[t * 32 + tid];
#pragma unroll 8
        for (int i = 0; i < 64; ++i) acc += h1l[i] * dw2[t * 64 * 32 + i * 32 + tid];
        v = gelu_exact(acc) * dw3[t * 32 + tid];
    }
#pragma unroll
    for (int off = 16; off >= 1; off >>= 1) v += __shfl_down(v, off, 64);
    if (tid == 0) out[b * T + t] = 1.f / (1.f + expf(-(v + db3[t])));
}

// ---------------------------------------------------------------------------
extern "C" void kernel_launch(void* const* d_in, const int* in_sizes, int n_in,
                              void* d_out, int out_size, void* d_ws, size_t ws_size,
                              hipStream_t stream) {
    const float* path = (const float*)d_in[0];
    const float* ts   = (const float*)d_in[1];
    const float* ew1  = (const float*)d_in[2];
    const float* eb1  = (const float*)d_in[3];
    const float* eg1  = (const float*)d_in[4];
    const float* ebe1 = (const float*)d_in[5];
    const float* ew2  = (const float*)d_in[6];
    const float* eb2  = (const float*)d_in[7];
    const float* eg2  = (const float*)d_in[8];
    const float* ebe2 = (const float*)d_in[9];
    const float* vw0  = (const float*)d_in[10];
    const float* vb0  = (const float*)d_in[11];
    const float* vg0  = (const float*)d_in[12];
    const float* vbe0 = (const float*)d_in[13];
    const float* vw1  = (const float*)d_in[14];
    const float* vb1  = (const float*)d_in[15];
    const float* vg1  = (const float*)d_in[16];
    const float* vbe1 = (const float*)d_in[17];
    const float* vw2  = (const float*)d_in[18];
    const float* vb2  = (const float*)d_in[19];
    const float* vg2  = (const float*)d_in[20];
    const float* vbe2 = (const float*)d_in[21];
    const float* vw3  = (const float*)d_in[22];
    const float* vb3  = (const float*)d_in[23];
    const float* wv   = (const float*)d_in[24];
    const float* bv   = (const float*)d_in[25];
    const float* wo   = (const float*)d_in[26];
    const float* bo   = (const float*)d_in[27];
    const float* dw1  = (const float*)d_in[28];
    const float* db1  = (const float*)d_in[29];
    const float* dw2  = (const float*)d_in[30];
    const float* db2  = (const float*)d_in[31];
    const float* dw3  = (const float*)d_in[32];
    const float* db3  = (const float*)d_in[33];

    char* ws = (char*)d_ws;
    size_t off = 0;
    auto take = [&](size_t bytes) { char* p = ws + off; off += (bytes + 255) & ~(size_t)255; return p; };
    uint32_t* Ach   = (uint32_t*)take((size_t)CH * B * ADW * 4);    // 128 MiB
    uint32_t* dxp   = (uint32_t*)take((size_t)NSTEP * B * 32 * 4);  // 1 MiB (padded rows)
    float*    bd3g  = (float*)take((size_t)NSTEP * B * H * 4);      // 4 MiB
    float*    dtb   = (float*)take(NSTEP * 4);
    float*    zbuf  = (float*)take((size_t)B * H * 4);
    float*    att   = (float*)take((size_t)B * H * 4);
    uint32_t* wcol  = (uint32_t*)take((size_t)160 * 512 * 4);       // 320 KB
    uint32_t* wp    = (uint32_t*)take((size_t)32768 * 32 * 4);      // 4 MiB

    packprep_kernel<<<4096 + B, 256, 0, stream>>>(
        vw0, vw1, vw2, vw3, wcol, wp,
        path, ts, ew1, eb1, eg1, ebe1, ew2, eb2, eg2, ebe2, vb3,
        zbuf, dxp, bd3g, dtb);
    for (int c = 0; c < NCH; ++c) {
        amm_kernel<<<2048, 256, 0, stream>>>(wp, dxp, Ach, c * CH);
        scan_kernel<<<B, 512, 0, stream>>>(wcol, Ach,
                                           vb0, vg0, vbe0, vb1, vg1, vbe1, vb2, vg2, vbe2,
                                           bd3g, dtb, zbuf, c * CH,
                                           (c == NCH - 1) ? 1 : 0,
                                           wv, bv, wo, bo, att);
    }
    dec_kernel<<<T * B, 64, 0, stream>>>(att, dw1, db1, dw2, db2, dw3, db3, (float*)d_out);
}